// Round 11
// baseline (94.330 us; speedup 1.0000x reference)
//
#include <hip/hip_runtime.h>
#include <hip/hip_bf16.h>

#define B_ 8
#define N_ 2048
#define D_ 512
#define DK_ 64

typedef float f32x4 __attribute__((ext_vector_type(4)));
typedef short bf16x8 __attribute__((ext_vector_type(8)));
typedef unsigned short u16;

__device__ __forceinline__ u16 f2bf(float f) {
  union { float f; unsigned u; } v; v.f = f;
  unsigned r = v.u + 0x7FFFu + ((v.u >> 16) & 1u);  // RNE, inputs finite
  return (u16)(r >> 16);
}

#define MFMA16(a, b, cacc) __builtin_amdgcn_mfma_f32_16x16x32_bf16((a), (b), (cacc), 0, 0, 0)

// lgkm-only barrier (validated R4/R10 incl. graph-replay revalidation):
// orders LDS ops across the barrier WITHOUT draining vmcnt; all in-flight
// vmem targets per-wave registers (no cross-wave hazard).
#define BARRIER_LGKM() do {                                   \
    asm volatile("s_waitcnt lgkmcnt(0)" ::: "memory");        \
    __builtin_amdgcn_s_barrier();                             \
    asm volatile("" ::: "memory");                            \
  } while (0)

// ===========================================================================
// Fragment layouts (every attn global load = 64 lanes x 16B contiguous 1KB):
//  Qf/Kf: elem((b*128 + slab)*2 + ks)*512 + lane*8 + i
//         holds  M[slab*16 + (lane&15)][ks*32 + (lane>>4)*8 + i]
//  Vf:    elem(((b*32 + dt)*32 + nt)*2 + ks)*512 + lane*8 + i
//         holds  X[nt*64 + ks*32 + (lane>>4)*8 + i][dt*16 + (lane&15)]
//         (j-linear: elem((b*32+dt)*64 + j)*512 for 32-kv window j)
// ===========================================================================

// ---------------------------------------------------------------------------
// Kernel 1 (validated, unchanged): X f32 -> Vf bf16 frag layout.
// ---------------------------------------------------------------------------
__global__ __launch_bounds__(256) void vt_kernel(const float* __restrict__ X,
                                                 u16* __restrict__ Vf) {
  int bid = blockIdx.x;
  int dt = bid & 7, nt = (bid >> 3) & 31, b = bid >> 8;
  int n0 = nt * 64, d0 = dt * 64;
  __shared__ u16 T[64 * 72];  // T[d_local][n_local]
  int t = threadIdx.x;
  const float* Xb = X + ((size_t)b * N_ + n0) * D_ + d0;
#pragma unroll
  for (int p = 0; p < 4; ++p) {
    int r = p * 16 + (t >> 4);      // n_local
    int c4 = (t & 15) * 4;          // d_local base
    f32x4 v = *reinterpret_cast<const f32x4*>(Xb + (size_t)r * D_ + c4);
#pragma unroll
    for (int j = 0; j < 4; ++j) T[(c4 + j) * 72 + r] = f2bf(v[j]);
  }
  __syncthreads();
  int w = t >> 6, l = t & 63, g = l >> 4, c = l & 15;
#pragma unroll
  for (int ks = 0; ks < 2; ++ks) {
    bf16x8 v = *reinterpret_cast<const bf16x8*>(&T[(w * 16 + c) * 72 + ks * 32 + 8 * g]);
    *reinterpret_cast<bf16x8*>(
        Vf + (((size_t)(b * 32 + dt * 4 + w) * 32 + nt) * 2 + ks) * 512 + l * 8) = v;
  }
}

// ---------------------------------------------------------------------------
// Kernel 2 (validated, unchanged): Qf = (h@WQ + bQ)/8, Kf = X@WK + bK.
// ---------------------------------------------------------------------------
__global__ __launch_bounds__(256) void proj_kernel(
    const float* __restrict__ h, const float* __restrict__ X,
    const float* __restrict__ WQ, const float* __restrict__ bQ,
    const float* __restrict__ WK, const float* __restrict__ bK,
    u16* __restrict__ Qf, u16* __restrict__ Kf) {
  int bid = blockIdx.x;
  int b = bid & 7, nt = bid >> 3;
  int n0 = nt * 64;
  int t = threadIdx.x, w = t >> 6, l = t & 63, g = l >> 4, c = l & 15;
  int arow = n0 + w * 16 + c;
  const float* hrow = h + ((size_t)b * N_ + arow) * D_;
  const float* Xrow = X + ((size_t)b * N_ + arow) * D_;
  f32x4 accq[4], acck[4];
#pragma unroll
  for (int cf = 0; cf < 4; ++cf) {
    accq[cf] = (f32x4){0.f, 0.f, 0.f, 0.f};
    acck[cf] = (f32x4){0.f, 0.f, 0.f, 0.f};
  }
  for (int k0 = 0; k0 < D_; k0 += 32) {
    bf16x8 ah, ax;
    {
      f32x4 h0 = *reinterpret_cast<const f32x4*>(hrow + k0 + 8 * g);
      f32x4 h1 = *reinterpret_cast<const f32x4*>(hrow + k0 + 8 * g + 4);
      f32x4 x0 = *reinterpret_cast<const f32x4*>(Xrow + k0 + 8 * g);
      f32x4 x1 = *reinterpret_cast<const f32x4*>(Xrow + k0 + 8 * g + 4);
#pragma unroll
      for (int i = 0; i < 4; ++i) {
        ah[i] = (short)f2bf(h0[i]); ah[i + 4] = (short)f2bf(h1[i]);
        ax[i] = (short)f2bf(x0[i]); ax[i + 4] = (short)f2bf(x1[i]);
      }
    }
#pragma unroll
    for (int cf = 0; cf < 4; ++cf) {
      bf16x8 bq, bk;
#pragma unroll
      for (int i = 0; i < 8; ++i) {
        int kk = k0 + 8 * g + i;
        bq[i] = (short)f2bf(WQ[(size_t)kk * DK_ + cf * 16 + c]);
        bk[i] = (short)f2bf(WK[(size_t)kk * DK_ + cf * 16 + c]);
      }
      accq[cf] = MFMA16(ah, bq, accq[cf]);
      acck[cf] = MFMA16(ax, bk, acck[cf]);
    }
  }
#pragma unroll
  for (int cf = 0; cf < 4; ++cf) {
    float vq = bQ[cf * 16 + c], vk = bK[cf * 16 + c];
    int ks = cf >> 1;
    int g2 = ((cf & 1) * 16 + c) >> 3;
    int i2 = c & 7;
#pragma unroll
    for (int r = 0; r < 4; ++r) {
      size_t e = ((size_t)(b * 128 + nt * 4 + w) * 2 + ks) * 512 +
                 (g2 * 16 + 4 * g + r) * 8 + i2;
      Qf[e] = f2bf((accq[cf][r] + vq) * 0.125f);
      Kf[e] = f2bf(acck[cf][r] + vk);
    }
  }
}

// ---------------------------------------------------------------------------
// attn: OCCUPANCY REGIME CHANGE (R6-R10 all ~52us at 8 waves/CU; every
// schedule permutation neutral -> latency-bound with no TLP). Now:
// 512 blocks x 512 threads, QBLK=32, 2 blocks/CU = 16 waves/CU = 4/SIMD.
// KVBLK=32, 64 windows. Wave w: PV d-slice w*64; S-duty (qh=w&1, kq=(w>>1)&1),
// waves 4-7 duplicate S (cheap: 2 MFMA + 4 exp) but only w<4 write P.
// K/V 2-deep register prefetch; ONE lgkm-only barrier per window.
// VGPR ~118 <= 128 for 4 waves/SIMD (__launch_bounds__(512,4)).
// ---------------------------------------------------------------------------
__global__ __launch_bounds__(512, 4) void attn_kernel(
    const u16* __restrict__ Qf, const u16* __restrict__ Kf,
    const u16* __restrict__ Vf, float* __restrict__ out) {
  int bid = blockIdx.x;
  int b = bid & 7, qt = bid >> 3;           // 64 q-tiles of 32
  int q0 = qt * 32;
  int t = threadIdx.x, w = t >> 6, l = t & 63, g = l >> 4, c = l & 15;
  int qh = w & 1, kq = (w >> 1) & 1, dup = w >> 2;

  __shared__ u16 Plds[2][32][76];   // P dbuf [q 32][kv 32], stride 76 (R8: 0-conflict)
  __shared__ float Lp[2][32];

  // resident Q A-frags: slab = qt*2 + qh
  bf16x8 aq[2];
#pragma unroll
  for (int ks = 0; ks < 2; ++ks)
    aq[ks] = *reinterpret_cast<const bf16x8*>(
        Qf + ((size_t)(b * 128 + qt * 2 + qh) * 2 + ks) * 512 + l * 8);

  f32x4 o[2][4];
#pragma unroll
  for (int a = 0; a < 2; ++a)
#pragma unroll
    for (int d = 0; d < 4; ++d) o[a][d] = (f32x4){0.f, 0.f, 0.f, 0.f};
  float lp[4] = {0.f, 0.f, 0.f, 0.f};

  // K frag (window j, ks): elem (b*256 + 4j + 2kq + ks)*512 + l*8
  const u16* Kbase = Kf + ((size_t)(b * 256 + 2 * kq)) * 512 + l * 8;
  // V frag (df, window j): elem ((b*32 + w*4 + df)*64 + j)*512 + l*8
  const u16* Vbase = Vf + ((size_t)(b * 32 + w * 4) * 64) * 512 + l * 8;

  bf16x8 kbuf[2][2], vbuf[2][4];

  // ---- prologue: K/V tiles 0,1; S(0); P(0)->buf0; barrier
#pragma unroll
  for (int j = 0; j < 2; ++j) {
#pragma unroll
    for (int ks = 0; ks < 2; ++ks)
      kbuf[j][ks] = *reinterpret_cast<const bf16x8*>(
          Kbase + (size_t)(4 * j + ks) * 512);
#pragma unroll
    for (int f = 0; f < 4; ++f)
      vbuf[j][f] = *reinterpret_cast<const bf16x8*>(
          Vbase + (size_t)(f * 64 + j) * 512);
  }
  {
    f32x4 s = (f32x4){0.f, 0.f, 0.f, 0.f};
    s = MFMA16(aq[0], kbuf[0][0], s);
    s = MFMA16(aq[1], kbuf[0][1], s);
#pragma unroll
    for (int r = 0; r < 4; ++r) {
      float p = __expf(s[r]); lp[r] += p;
      if (dup == 0) Plds[0][qh * 16 + 4 * g + r][kq * 16 + c] = f2bf(p);
    }
  }
  BARRIER_LGKM();

  // body(i): load K(i+2)->kbuf[i&1]; S(i+1) from kbuf[(i+1)&1]; P(i+1);
  //          PV(i) from Plds[i&1]+vbuf[i&1]; load V(i+2)->vbuf[i&1]; barrier.
  auto body = [&](bf16x8 (&kFree)[2], bf16x8 (&kS)[2],
                  bf16x8 (&vCur)[4], int i) {
    const int jn = (i + 2) & 63;
    const int pbW = (i + 1) & 1, pbR = i & 1;

    // K prefetch early (slot freed by body(i-1)'s S)
#pragma unroll
    for (int ks = 0; ks < 2; ++ks)
      kFree[ks] = *reinterpret_cast<const bf16x8*>(
          Kbase + (size_t)(4 * jn + ks) * 512);

    // ---- S(i+1): 16q x 32kv in ONE MFMA chain (K-dim 32)
    f32x4 s = (f32x4){0.f, 0.f, 0.f, 0.f};
    s = MFMA16(aq[0], kS[0], s);
    s = MFMA16(aq[1], kS[1], s);

    // ---- exp + gated P-write
#pragma unroll
    for (int r = 0; r < 4; ++r) {
      float p = __expf(s[r]); lp[r] += p;
      if (dup == 0) Plds[pbW][qh * 16 + 4 * g + r][kq * 16 + c] = f2bf(p);
    }

    // ---- PV(i): P A-frags (b128 row reads), V from registers
    bf16x8 pa0 = *reinterpret_cast<const bf16x8*>(&Plds[pbR][c][8 * g]);
    bf16x8 pa1 = *reinterpret_cast<const bf16x8*>(&Plds[pbR][16 + c][8 * g]);
    __builtin_amdgcn_s_setprio(1);
#pragma unroll
    for (int df = 0; df < 4; ++df) {
      o[0][df] = MFMA16(pa0, vCur[df], o[0][df]);
      o[1][df] = MFMA16(pa1, vCur[df], o[1][df]);
    }
    __builtin_amdgcn_s_setprio(0);

    // V prefetch after PV consumed the slot (WAR handled by compiler)
#pragma unroll
    for (int f = 0; f < 4; ++f)
      vCur[f] = *reinterpret_cast<const bf16x8*>(
          Vbase + (size_t)(f * 64 + jn) * 512);

    BARRIER_LGKM();
  };

#pragma unroll 1
  for (int i = 0; i < 62; i += 2) {
    body(kbuf[0], kbuf[1], vbuf[0], i);
    body(kbuf[1], kbuf[0], vbuf[1], i + 1);
  }
  body(kbuf[0], kbuf[1], vbuf[0], 62);

  // ---- epilogue: PV(63) (P in buf1, V in vbuf[1])
  {
    bf16x8 pa0 = *reinterpret_cast<const bf16x8*>(&Plds[1][c][8 * g]);
    bf16x8 pa1 = *reinterpret_cast<const bf16x8*>(&Plds[1][16 + c][8 * g]);
#pragma unroll
    for (int df = 0; df < 4; ++df) {
      o[0][df] = MFMA16(pa0, vbuf[1][df], o[0][df]);
      o[1][df] = MFMA16(pa1, vbuf[1][df], o[1][df]);
    }
  }

  // ---- denominator: reduce lp over 16 c-lanes; combine 2 kq halves
#pragma unroll
  for (int r = 0; r < 4; ++r) {
    float v = lp[r];
    v += __shfl_xor(v, 1); v += __shfl_xor(v, 2);
    v += __shfl_xor(v, 4); v += __shfl_xor(v, 8);
    lp[r] = v;
  }
  if (dup == 0 && c == 0) {
#pragma unroll
    for (int r = 0; r < 4; ++r) Lp[kq][qh * 16 + 4 * g + r] = lp[r];
  }
  __syncthreads();

  float* outb = out + ((size_t)b * N_ + q0) * D_;
#pragma unroll
  for (int a = 0; a < 2; ++a)
#pragma unroll
    for (int r = 0; r < 4; ++r) {
      int ql = a * 16 + 4 * g + r;
      float L = Lp[0][ql] + Lp[1][ql];
      float inv = 1.0f / L;
#pragma unroll
      for (int df = 0; df < 4; ++df)
        outb[(size_t)ql * D_ + w * 64 + df * 16 + c] = o[a][df][r] * inv;
    }
}

// ---------------------------------------------------------------------------
extern "C" void kernel_launch(void* const* d_in, const int* in_sizes, int n_in,
                              void* d_out, int out_size, void* d_ws, size_t ws_size,
                              hipStream_t stream) {
  const float* X  = (const float*)d_in[0];
  const float* h  = (const float*)d_in[1];
  const float* WQ = (const float*)d_in[2];
  const float* bQ = (const float*)d_in[3];
  const float* WK = (const float*)d_in[4];
  const float* bK = (const float*)d_in[5];
  float* out = (float*)d_out;

  u16* Vf = (u16*)d_ws;                                // 16 MB
  u16* Qf = Vf + (size_t)B_ * D_ * N_;                 // 2 MB
  u16* Kf = Qf + (size_t)B_ * N_ * DK_;                // 2 MB

  vt_kernel<<<dim3(2048), dim3(256), 0, stream>>>(X, Vf);
  proj_kernel<<<dim3(256), dim3(256), 0, stream>>>(h, X, WQ, bQ, WK, bK, Qf, Kf);
  attn_kernel<<<dim3(512), dim3(512), 0, stream>>>(Qf, Kf, Vf, out);
}